// Round 6
// baseline (373.640 us; speedup 1.0000x reference)
//
#include <hip/hip_runtime.h>
#include <hip/hip_bf16.h>
#include <hip/hip_cooperative_groups.h>

namespace cg = cooperative_groups;

#define N_ROWS 4096
#define DIM 512
#define TWO_N 8192
#define NTILE 64                 // 8192 / 128
#define NTRI  (NTILE * (NTILE + 1) / 2)   // 2080 upper-tri 128x128 blocks
#define GRID  1024               // cooperative grid: 4 blocks/CU x 256 CU

typedef __bf16 bf16x8 __attribute__((ext_vector_type(8)));
typedef float  f32x4  __attribute__((ext_vector_type(4)));

// ---------------------------------------------------------------------------
// round-to-nearest-even float -> bf16 bits
__device__ inline unsigned short f2bf(float f) {
    unsigned int u = __float_as_uint(f);
    u += 0x7fffu + ((u >> 16) & 1u);
    return (unsigned short)(u >> 16);
}

// async global -> LDS, 16 bytes per lane (wave-uniform LDS base + lane*16)
__device__ inline void g2l16(const void* g, void* l) {
    __builtin_amdgcn_global_load_lds(
        (const __attribute__((address_space(1))) void*)g,
        (__attribute__((address_space(3))) void*)l,
        16, 0, 0);
}

// ---------------------------------------------------------------------------
// wave-per-row normalize: lane handles 8 consecutive dims (2x float4 in,
// 1x uint4 = 8 bf16 out per matrix). shfl_xor all-lane reduce, no LDS.
__device__ inline void normalize_row(const float* __restrict__ ei,
                                     const float* __restrict__ ej,
                                     unsigned short* __restrict__ zb,
                                     float* __restrict__ pos,
                                     float* __restrict__ denom,
                                     int r, int lane) {
    const float4* pi = (const float4*)(ei + (size_t)r * DIM);
    const float4* pj = (const float4*)(ej + (size_t)r * DIM);
    float4 a0 = pi[lane * 2], a1 = pi[lane * 2 + 1];
    float4 b0 = pj[lane * 2], b1 = pj[lane * 2 + 1];

    float si  = a0.x*a0.x + a0.y*a0.y + a0.z*a0.z + a0.w*a0.w
              + a1.x*a1.x + a1.y*a1.y + a1.z*a1.z + a1.w*a1.w;
    float sj  = b0.x*b0.x + b0.y*b0.y + b0.z*b0.z + b0.w*b0.w
              + b1.x*b1.x + b1.y*b1.y + b1.z*b1.z + b1.w*b1.w;
    float sij = a0.x*b0.x + a0.y*b0.y + a0.z*b0.z + a0.w*b0.w
              + a1.x*b1.x + a1.y*b1.y + a1.z*b1.z + a1.w*b1.w;

    #pragma unroll
    for (int o = 1; o < 64; o <<= 1) {
        si  += __shfl_xor(si, o);
        sj  += __shfl_xor(sj, o);
        sij += __shfl_xor(sij, o);
    }
    float rni = 1.0f / fmaxf(sqrtf(si), 1e-12f);
    float rnj = 1.0f / fmaxf(sqrtf(sj), 1e-12f);
    if (lane == 0) {
        pos[r] = sij * rni * rnj;
        denom[r] = 0.0f;
        denom[r + N_ROWS] = 0.0f;
    }
    union { unsigned short u[8]; uint4 v; } zi, zj;
    zi.u[0] = f2bf(a0.x * rni); zi.u[1] = f2bf(a0.y * rni);
    zi.u[2] = f2bf(a0.z * rni); zi.u[3] = f2bf(a0.w * rni);
    zi.u[4] = f2bf(a1.x * rni); zi.u[5] = f2bf(a1.y * rni);
    zi.u[6] = f2bf(a1.z * rni); zi.u[7] = f2bf(a1.w * rni);
    zj.u[0] = f2bf(b0.x * rnj); zj.u[1] = f2bf(b0.y * rnj);
    zj.u[2] = f2bf(b0.z * rnj); zj.u[3] = f2bf(b0.w * rnj);
    zj.u[4] = f2bf(b1.x * rnj); zj.u[5] = f2bf(b1.y * rnj);
    zj.u[6] = f2bf(b1.z * rnj); zj.u[7] = f2bf(b1.w * rnj);
    ((uint4*)(zb + (size_t)r * DIM))[lane] = zi.v;
    ((uint4*)(zb + (size_t)(r + N_ROWS) * DIM))[lane] = zj.v;
}

// ---------------------------------------------------------------------------
// Mega kernel (cooperative): phase 1 normalize -> grid.sync -> phase 2
// tile-looped v4 gemm (128x128, BK=64, 4 blocks/CU) -> grid.sync ->
// phase 3 loss. Removes two kernel-launch gaps per iteration.
__global__ __launch_bounds__(256, 4) void mega_kernel(
        const float* __restrict__ ei, const float* __restrict__ ej,
        unsigned short* __restrict__ zb, float* __restrict__ pos,
        float* __restrict__ denom, float* __restrict__ out) {
    const int tid  = threadIdx.x;
    const int wave = tid >> 6;
    const int lane = tid & 63;

    __shared__ __align__(16) unsigned short As[128 * 64];
    __shared__ __align__(16) unsigned short Bs[128 * 64];

    // ---------------- phase 1: normalize (4 rows per block) ----------------
    {
        int r = blockIdx.x * 4 + wave;           // 1024*4 = 4096 rows
        normalize_row(ei, ej, zb, pos, denom, r, lane);
        if (blockIdx.x == 0 && tid == 0) out[0] = 0.0f;
    }
    cg::this_grid().sync();

    // ---------------- phase 2: upper-tri tiled GEMM + exp-sums -------------
    const int quad = lane >> 4;          // 0..3
    const int m    = lane & 15;          // 0..15
    const int wm   = (wave >> 1) * 64;   // wave row offset in tile
    const int wn   = (wave & 1) * 64;    // wave col offset in tile
    const int srow8 = lane >> 3;                     // staging row in chunk
    const int sk    = (((lane & 7) ^ srow8) * 8);    // pre-swizzled granule

    for (int tix = blockIdx.x; tix < NTRI; tix += GRID) {
        // linear index -> (by, bx), by <= bx
        int by = (int)(0.5f * (2.0f * NTILE + 1.0f -
                  sqrtf((2.0f * NTILE + 1.0f) * (2.0f * NTILE + 1.0f) - 8.0f * tix)));
        while ((by + 1) * NTILE - ((by + 1) * by) / 2 <= tix) ++by;
        while (by * NTILE - (by * (by - 1)) / 2 > tix) --by;
        const int bx = by + (tix - (by * NTILE - (by * (by - 1)) / 2));
        const int rb = by * 128;
        const int cb = bx * 128;
        const bool diag = (rb == cb);

        f32x4 acc[4][4];
        #pragma unroll
        for (int i = 0; i < 4; ++i)
            #pragma unroll
            for (int j = 0; j < 4; ++j)
                #pragma unroll
                for (int r = 0; r < 4; ++r) acc[i][j][r] = 0.0f;

        for (int it = 0; it < DIM / 64; ++it) {
            __syncthreads();             // prev ds_reads / epilogue LDS done
            const int k0 = it * 64;
            #pragma unroll
            for (int cc = 0; cc < 4; ++cc) {
                int c   = 4 * wave + cc;
                int row = c * 8 + srow8;
                g2l16(zb + (size_t)(rb + row) * DIM + k0 + sk, As + c * 512);
                g2l16(zb + (size_t)(cb + row) * DIM + k0 + sk, Bs + c * 512);
            }
            __syncthreads();             // implicit vmcnt drain: tile visible

            #pragma unroll
            for (int h = 0; h < 2; ++h) {
                bf16x8 af[4], bfr[4];
                const int sl = ((((h << 2) | quad) ^ (m & 7)) * 8);
                #pragma unroll
                for (int i = 0; i < 4; ++i)
                    af[i] = *(const bf16x8*)(As + (wm + i * 16 + m) * 64 + sl);
                #pragma unroll
                for (int j = 0; j < 4; ++j)
                    bfr[j] = *(const bf16x8*)(Bs + (wn + j * 16 + m) * 64 + sl);

                #pragma unroll
                for (int i = 0; i < 4; ++i)
                    #pragma unroll
                    for (int j = 0; j < 4; ++j)
                        acc[i][j] = __builtin_amdgcn_mfma_f32_16x16x32_bf16(
                            af[i], bfr[j], acc[i][j], 0, 0, 0);
            }
        }
        __syncthreads();                 // all ds_reads done -> reuse As

        float* rs = (float*)As;          // rowsum[128] | colsum[128]
        float* cs = rs + 128;
        if (tid < 128) { rs[tid] = 0.0f; cs[tid] = 0.0f; }
        __syncthreads();

        float colsum[4] = {0.0f, 0.0f, 0.0f, 0.0f};
        #pragma unroll
        for (int i = 0; i < 4; ++i) {
            #pragma unroll
            for (int r = 0; r < 4; ++r) {
                int lrow = wm + i * 16 + quad * 4 + r;
                int grow = rb + lrow;
                float s = 0.0f;
                #pragma unroll
                for (int j = 0; j < 4; ++j) {
                    int gcol = cb + wn + j * 16 + m;
                    float v  = __expf(2.0f * acc[i][j][r]);
                    v = (grow == gcol) ? 0.0f : v;
                    s += v;
                    colsum[j] += v;
                }
                s += __shfl_xor(s, 1);
                s += __shfl_xor(s, 2);
                s += __shfl_xor(s, 4);
                s += __shfl_xor(s, 8);
                if (m == 0) atomicAdd(&rs[lrow], s);
            }
        }
        if (!diag) {
            #pragma unroll
            for (int j = 0; j < 4; ++j) {
                float s = colsum[j];
                s += __shfl_xor(s, 16);
                s += __shfl_xor(s, 32);
                if (quad == 0) atomicAdd(&cs[wn + j * 16 + m], s);
            }
        }
        __syncthreads();
        if (tid < 128) {
            atomicAdd(&denom[rb + tid], rs[tid]);
            if (!diag) atomicAdd(&denom[cb + tid], cs[tid]);
        }
    }
    cg::this_grid().sync();

    // ---------------- phase 3: loss reduction (blocks 0..31) ---------------
    if (blockIdx.x < TWO_N / 256) {
        int r = blockIdx.x * 256 + tid;
        float s = __logf(denom[r]) - 2.0f * pos[r & (N_ROWS - 1)];
        for (int o = 32; o; o >>= 1) s += __shfl_down(s, o);
        float* red = (float*)As;
        if ((tid & 63) == 0) red[wave] = s;
        __syncthreads();
        if (tid == 0)
            atomicAdd(out, (red[0] + red[1] + red[2] + red[3]) / (float)TWO_N);
    }
}

// ---------------------------------------------------------------------------
// Fallback path (classic 3-launch) in case cooperative launch is rejected.
__global__ void normalize_fast_kernel(const float* __restrict__ ei,
                                      const float* __restrict__ ej,
                                      unsigned short* __restrict__ zb,
                                      float* __restrict__ pos,
                                      float* __restrict__ denom,
                                      float* __restrict__ out) {
    int wave = threadIdx.x >> 6, lane = threadIdx.x & 63;
    int r = blockIdx.x * 4 + wave;
    normalize_row(ei, ej, zb, pos, denom, r, lane);
    if (blockIdx.x == 0 && threadIdx.x == 0) out[0] = 0.0f;
}

__global__ __launch_bounds__(256, 4) void gemm_exp_kernel(
        const unsigned short* __restrict__ zb,
        float* __restrict__ denom) {
    const int t = blockIdx.x;
    int by = (int)(0.5f * (2.0f * NTILE + 1.0f -
              sqrtf((2.0f * NTILE + 1.0f) * (2.0f * NTILE + 1.0f) - 8.0f * t)));
    while ((by + 1) * NTILE - ((by + 1) * by) / 2 <= t) ++by;
    while (by * NTILE - (by * (by - 1)) / 2 > t) --by;
    const int bx = by + (t - (by * NTILE - (by * (by - 1)) / 2));
    const int rb = by * 128, cb = bx * 128;
    const bool diag = (rb == cb);

    const int tid  = threadIdx.x;
    const int wave = tid >> 6;
    const int lane = tid & 63;
    const int quad = lane >> 4;
    const int m    = lane & 15;
    const int wm   = (wave >> 1) * 64;
    const int wn   = (wave & 1) * 64;

    __shared__ __align__(16) unsigned short As[128 * 64];
    __shared__ __align__(16) unsigned short Bs[128 * 64];

    f32x4 acc[4][4];
    #pragma unroll
    for (int i = 0; i < 4; ++i)
        #pragma unroll
        for (int j = 0; j < 4; ++j)
            #pragma unroll
            for (int r = 0; r < 4; ++r) acc[i][j][r] = 0.0f;

    const int srow8 = lane >> 3;
    const int sk    = (((lane & 7) ^ srow8) * 8);

    for (int it = 0; it < DIM / 64; ++it) {
        if (it) __syncthreads();
        const int k0 = it * 64;
        #pragma unroll
        for (int cc = 0; cc < 4; ++cc) {
            int c   = 4 * wave + cc;
            int row = c * 8 + srow8;
            g2l16(zb + (size_t)(rb + row) * DIM + k0 + sk, As + c * 512);
            g2l16(zb + (size_t)(cb + row) * DIM + k0 + sk, Bs + c * 512);
        }
        __syncthreads();

        #pragma unroll
        for (int h = 0; h < 2; ++h) {
            bf16x8 af[4], bfr[4];
            const int sl = ((((h << 2) | quad) ^ (m & 7)) * 8);
            #pragma unroll
            for (int i = 0; i < 4; ++i)
                af[i] = *(const bf16x8*)(As + (wm + i * 16 + m) * 64 + sl);
            #pragma unroll
            for (int j = 0; j < 4; ++j)
                bfr[j] = *(const bf16x8*)(Bs + (wn + j * 16 + m) * 64 + sl);
            #pragma unroll
            for (int i = 0; i < 4; ++i)
                #pragma unroll
                for (int j = 0; j < 4; ++j)
                    acc[i][j] = __builtin_amdgcn_mfma_f32_16x16x32_bf16(
                        af[i], bfr[j], acc[i][j], 0, 0, 0);
        }
    }
    __syncthreads();

    float* rs = (float*)As;
    float* cs = rs + 128;
    if (tid < 128) { rs[tid] = 0.0f; cs[tid] = 0.0f; }
    __syncthreads();

    float colsum[4] = {0.0f, 0.0f, 0.0f, 0.0f};
    #pragma unroll
    for (int i = 0; i < 4; ++i) {
        #pragma unroll
        for (int r = 0; r < 4; ++r) {
            int lrow = wm + i * 16 + quad * 4 + r;
            int grow = rb + lrow;
            float s = 0.0f;
            #pragma unroll
            for (int j = 0; j < 4; ++j) {
                int gcol = cb + wn + j * 16 + m;
                float v  = __expf(2.0f * acc[i][j][r]);
                v = (grow == gcol) ? 0.0f : v;
                s += v;
                colsum[j] += v;
            }
            s += __shfl_xor(s, 1);
            s += __shfl_xor(s, 2);
            s += __shfl_xor(s, 4);
            s += __shfl_xor(s, 8);
            if (m == 0) atomicAdd(&rs[lrow], s);
        }
    }
    if (!diag) {
        #pragma unroll
        for (int j = 0; j < 4; ++j) {
            float s = colsum[j];
            s += __shfl_xor(s, 16);
            s += __shfl_xor(s, 32);
            if (quad == 0) atomicAdd(&cs[wn + j * 16 + m], s);
        }
    }
    __syncthreads();
    if (tid < 128) {
        atomicAdd(&denom[rb + tid], rs[tid]);
        if (!diag) atomicAdd(&denom[cb + tid], cs[tid]);
    }
}

__global__ void loss_kernel(const float* __restrict__ pos,
                            const float* __restrict__ denom,
                            float* __restrict__ out) {
    int r = blockIdx.x * 256 + threadIdx.x;
    float s = __logf(denom[r]) - 2.0f * pos[r & (N_ROWS - 1)];
    for (int o = 32; o; o >>= 1) s += __shfl_down(s, o);
    __shared__ float red[4];
    int t = threadIdx.x;
    if ((t & 63) == 0) red[t >> 6] = s;
    __syncthreads();
    if (t == 0)
        atomicAdd(out, (red[0] + red[1] + red[2] + red[3]) / (float)TWO_N);
}

// ---------------------------------------------------------------------------
extern "C" void kernel_launch(void* const* d_in, const int* in_sizes, int n_in,
                              void* d_out, int out_size, void* d_ws, size_t ws_size,
                              hipStream_t stream) {
    const float* ei = (const float*)d_in[0];
    const float* ej = (const float*)d_in[1];

    // ws layout: zb (bf16, 2N*D = 8 MB) | pos (N f32) | denom (2N f32)
    unsigned short* zb  = (unsigned short*)d_ws;
    float* pos   = (float*)((char*)d_ws + (size_t)TWO_N * DIM * sizeof(unsigned short));
    float* denom = pos + N_ROWS;
    float* out   = (float*)d_out;

    void* kargs[] = {(void*)&ei, (void*)&ej, (void*)&zb,
                     (void*)&pos, (void*)&denom, (void*)&out};
    hipError_t err = hipLaunchCooperativeKernel(
        (const void*)mega_kernel, dim3(GRID), dim3(256), kargs, 0, stream);
    if (err != hipSuccess) {
        (void)hipGetLastError();   // clear sticky error, use classic path
        normalize_fast_kernel<<<GRID, 256, 0, stream>>>(ei, ej, zb, pos, denom, out);
        gemm_exp_kernel<<<NTRI, 256, 0, stream>>>(zb, denom);
        loss_kernel<<<TWO_N / 256, 256, 0, stream>>>(pos, denom, out);
    }
}

// Round 7
// 135.807 us; speedup vs baseline: 2.7513x; 2.7513x over previous
//
#include <hip/hip_runtime.h>
#include <hip/hip_bf16.h>

#define N_ROWS 4096
#define DIM 512
#define TWO_N 8192
#define NT2   32                 // 8192 / 256
#define NTRI2 (NT2 * (NT2 + 1) / 2)   // 528 upper-tri 256x256 blocks

typedef __bf16 bf16x8 __attribute__((ext_vector_type(8)));
typedef float  f32x4  __attribute__((ext_vector_type(4)));

// ---------------------------------------------------------------------------
__device__ inline unsigned short f2bf(float f) {
    unsigned int u = __float_as_uint(f);
    u += 0x7fffu + ((u >> 16) & 1u);
    return (unsigned short)(u >> 16);
}

__device__ inline void g2l16(const void* g, void* l) {
    __builtin_amdgcn_global_load_lds(
        (const __attribute__((address_space(1))) void*)g,
        (__attribute__((address_space(3))) void*)l,
        16, 0, 0);
}

// ---------------------------------------------------------------------------
// Kernel 1: normalize (proven R0-R5 version, unchanged).
__global__ void normalize_kernel(const float* __restrict__ ei,
                                 const float* __restrict__ ej,
                                 unsigned short* __restrict__ zb,
                                 float* __restrict__ pos,
                                 float* __restrict__ denom,
                                 float* __restrict__ out) {
    int r = blockIdx.x;
    int t = threadIdx.x;
    const float2 vi = ((const float2*)(ei + (size_t)r * DIM))[t];
    const float2 vj = ((const float2*)(ej + (size_t)r * DIM))[t];
    float si  = vi.x * vi.x + vi.y * vi.y;
    float sj  = vj.x * vj.x + vj.y * vj.y;
    float sij = vi.x * vj.x + vi.y * vj.y;

    for (int o = 32; o; o >>= 1) {
        si  += __shfl_down(si, o);
        sj  += __shfl_down(sj, o);
        sij += __shfl_down(sij, o);
    }
    __shared__ float red[3][4];
    int wave = t >> 6, lane = t & 63;
    if (lane == 0) { red[0][wave] = si; red[1][wave] = sj; red[2][wave] = sij; }
    __syncthreads();
    si  = red[0][0] + red[0][1] + red[0][2] + red[0][3];
    sj  = red[1][0] + red[1][1] + red[1][2] + red[1][3];
    sij = red[2][0] + red[2][1] + red[2][2] + red[2][3];

    float rni = 1.0f / fmaxf(sqrtf(si), 1e-12f);
    float rnj = 1.0f / fmaxf(sqrtf(sj), 1e-12f);
    if (t == 0) {
        pos[r] = sij * rni * rnj;
        denom[r] = 0.0f;
        denom[r + N_ROWS] = 0.0f;
        if (r == 0) out[0] = 0.0f;
    }
    ushort2 zi2 = make_ushort2(f2bf(vi.x * rni), f2bf(vi.y * rni));
    ushort2 zj2 = make_ushort2(f2bf(vj.x * rnj), f2bf(vj.y * rnj));
    ((ushort2*)(zb + (size_t)r * DIM))[t] = zi2;
    ((ushort2*)(zb + (size_t)(r + N_ROWS) * DIM))[t] = zj2;
}

// ---------------------------------------------------------------------------
// Kernel 2 (v7): faithful m201-template 8-phase 256x256 GEMM.
//  - 8 waves (2M x 4N), BK=64, per-wave C = 128x64 (acc[8][4]).
//  - LDS: A[2 dbuf][2 halves][128x64], B same = 128 KB. Buffer = tile&1.
//  - Per 8-phase iter (K-tiles t, t+1): phase = {ds_read quadrant frags
//    (12/8/4/0, register-amortized), stage half-tiles into just-retired
//    regions, barrier, lgkmcnt(0)+sched_barrier, setprio(1)+16 MFMA+
//    setprio(0), barrier}.
//  - vmcnt ONLY at phases 0 and 4, always counted (8), never drained in
//    the main loop (tail iter uses vmcnt(0) at ph4). Verified windows:
//      A[buf] reads retire by ph1-close -> stage A@t+2 at ph2;
//      B[buf] reads retire by ph2-close -> stage B@t+2 at ph3;
//      (same +4 for buf1 at ph6/ph7).
//    vmcnt: at ph0 outstanding 16 (A_t,B_t,A_t+1,B_t+1) -> wait 8 lands
//    A_t,B_t; at ph4 outstanding 16 -> wait 8 lands A_t+1,B_t+1.
//  - Granule swizzle (PMC-proven, 0 conflicts): row holds at phys 16B
//    slot s the logical granule s^(row&7); staged via pre-swizzled
//    global source, linear LDS dest; read slot ((kk*4+quad)^(m&7)).
__global__ __launch_bounds__(512, 2) void gemm_exp_kernel(
        const unsigned short* __restrict__ zb,
        float* __restrict__ denom) {
    const int t0 = blockIdx.x;
    int by = (int)(0.5f * (2.0f * NT2 + 1.0f -
              sqrtf((2.0f * NT2 + 1.0f) * (2.0f * NT2 + 1.0f) - 8.0f * t0)));
    while ((by + 1) * NT2 - ((by + 1) * by) / 2 <= t0) ++by;
    while (by * NT2 - (by * (by - 1)) / 2 > t0) --by;
    const int bx = by + (t0 - (by * NT2 - (by * (by - 1)) / 2));

    const int rb = by * 256;
    const int cb = bx * 256;
    const bool diag = (rb == cb);

    const int tid  = threadIdx.x;
    const int wave = tid >> 6;           // 0..7
    const int lane = tid & 63;
    const int quad = lane >> 4;
    const int m    = lane & 15;
    const int wm   = (wave >> 2) * 128;  // A row-half (0/128)
    const int wn   = (wave & 3) * 64;    // B col-quarter (0/64/128/192)

    __shared__ __align__(16) unsigned short AL[2][16384];  // [buf][half*8192+...]
    __shared__ __align__(16) unsigned short BL[2][16384];

    f32x4 acc[8][4];
    #pragma unroll
    for (int i = 0; i < 8; ++i)
        #pragma unroll
        for (int j = 0; j < 4; ++j)
            #pragma unroll
            for (int r = 0; r < 4; ++r) acc[i][j][r] = 0.0f;

    // staging: half-tile = 128 rows x 64 ush = 16KB = 2 g2l16/thread.
    // thread covers rows r8 and 64+r8 of the half; src granule pre-swizzled.
    const int r8 = tid >> 3;                               // 0..63
    const int sk = (((lane & 7) ^ ((lane >> 3) & 7)) * 8); // pre-swizzle

    auto stA = [&](int b, int tt) {
        #pragma unroll
        for (int hh = 0; hh < 2; ++hh)
            #pragma unroll
            for (int rr = 0; rr < 128; rr += 64)
                g2l16(zb + (size_t)(rb + hh * 128 + rr + r8) * DIM + tt * 64 + sk,
                      &AL[b][hh * 8192 + rr * 64 + wave * 512]);
    };
    auto stB = [&](int b, int tt) {
        #pragma unroll
        for (int hh = 0; hh < 2; ++hh)
            #pragma unroll
            for (int rr = 0; rr < 128; rr += 64)
                g2l16(zb + (size_t)(cb + hh * 128 + rr + r8) * DIM + tt * 64 + sk,
                      &BL[b][hh * 8192 + rr * 64 + wave * 512]);
    };

    const unsigned short* aB0 = &AL[0][(wm >> 7) * 8192];
    const unsigned short* aB1 = &AL[1][(wm >> 7) * 8192];
    const unsigned short* bB0 = &BL[0][(wn >> 7) * 8192 + (wn & 64) * 64];
    const unsigned short* bB1 = &BL[1][(wn >> 7) * 8192 + (wn & 64) * 64];

#define RDF(dst, base, FR, KK)                                               \
    dst = *(const bf16x8*)((base) + ((FR) * 16 + m) * 64 +                   \
                           ((((KK) << 2) | quad) ^ (m & 7)) * 8)

#define CLUSTER(Aarr, Barr, IO, JO) do {                                     \
    __builtin_amdgcn_s_setprio(1);                                           \
    _Pragma("unroll")                                                        \
    for (int i_ = 0; i_ < 4; ++i_)                                           \
        _Pragma("unroll")                                                    \
        for (int j_ = 0; j_ < 2; ++j_)                                       \
            _Pragma("unroll")                                                \
            for (int k_ = 0; k_ < 2; ++k_)                                   \
                acc[(IO) + i_][(JO) + j_] =                                  \
                    __builtin_amdgcn_mfma_f32_16x16x32_bf16(                 \
                        Aarr[i_][k_], Barr[j_][k_],                          \
                        acc[(IO) + i_][(JO) + j_], 0, 0, 0);                 \
    __builtin_amdgcn_s_setprio(0);                                           \
} while (0)

#define BAR()   do { __builtin_amdgcn_s_barrier();                           \
                     __builtin_amdgcn_sched_barrier(0); } while (0)
#define LGKM0() do { asm volatile("s_waitcnt lgkmcnt(0)" ::: "memory");      \
                     __builtin_amdgcn_sched_barrier(0); } while (0)

    // prologue: stage tiles 0 (buf0) and 1 (buf1); oldest = A0,B0.
    stA(0, 0); stB(0, 0); stA(1, 1); stB(1, 1);

    bf16x8 afA[4][2], afB[4][2], bfA[2][2], bfB[2][2];

    #pragma unroll 1
    for (int t = 0; t < 8; t += 2) {
        // ---- phase 0: tile t, Q(r0-3, c0-1) ----
        asm volatile("s_waitcnt vmcnt(8)" ::: "memory");
        BAR();
        #pragma unroll
        for (int i = 0; i < 4; ++i) { RDF(afA[i][0], aB0, i, 0); RDF(afA[i][1], aB0, i, 1); }
        #pragma unroll
        for (int j = 0; j < 2; ++j) { RDF(bfA[j][0], bB0, j, 0); RDF(bfA[j][1], bB0, j, 1); }
        BAR(); LGKM0();
        CLUSTER(afA, bfA, 0, 0);
        BAR();

        // ---- phase 1: Q(r4-7, c0-1) ----
        #pragma unroll
        for (int i = 0; i < 4; ++i) { RDF(afB[i][0], aB0, 4 + i, 0); RDF(afB[i][1], aB0, 4 + i, 1); }
        BAR(); LGKM0();
        CLUSTER(afB, bfA, 4, 0);
        BAR();

        // ---- phase 2: Q(r0-3, c2-3); stage A <- t+2 (A[0] reads retired ph1) ----
        #pragma unroll
        for (int j = 0; j < 2; ++j) { RDF(bfB[j][0], bB0, 2 + j, 0); RDF(bfB[j][1], bB0, 2 + j, 1); }
        if (t < 6) stA(0, t + 2);
        BAR(); LGKM0();
        CLUSTER(afA, bfB, 0, 2);
        BAR();

        // ---- phase 3: Q(r4-7, c2-3); stage B <- t+2 (B[0] reads retired ph2) ----
        if (t < 6) stB(0, t + 2);
        BAR(); LGKM0();
        CLUSTER(afB, bfB, 4, 2);
        BAR();

        // ---- phase 4: tile t+1, Q(r0-3, c0-1) ----
        if (t < 6) { asm volatile("s_waitcnt vmcnt(8)" ::: "memory"); }
        else       { asm volatile("s_waitcnt vmcnt(0)" ::: "memory"); }
        BAR();
        #pragma unroll
        for (int i = 0; i < 4; ++i) { RDF(afA[i][0], aB1, i, 0); RDF(afA[i][1], aB1, i, 1); }
        #pragma unroll
        for (int j = 0; j < 2; ++j) { RDF(bfA[j][0], bB1, j, 0); RDF(bfA[j][1], bB1, j, 1); }
        BAR(); LGKM0();
        CLUSTER(afA, bfA, 0, 0);
        BAR();

        // ---- phase 5: Q(r4-7, c0-1) ----
        #pragma unroll
        for (int i = 0; i < 4; ++i) { RDF(afB[i][0], aB1, 4 + i, 0); RDF(afB[i][1], aB1, 4 + i, 1); }
        BAR(); LGKM0();
        CLUSTER(afB, bfA, 4, 0);
        BAR();

        // ---- phase 6: Q(r0-3, c2-3); stage A <- t+3 ----
        #pragma unroll
        for (int j = 0; j < 2; ++j) { RDF(bfB[j][0], bB1, 2 + j, 0); RDF(bfB[j][1], bB1, 2 + j, 1); }
        if (t < 6) stA(1, t + 3);
        BAR(); LGKM0();
        CLUSTER(afA, bfB, 0, 2);
        BAR();

        // ---- phase 7: Q(r4-7, c2-3); stage B <- t+3 ----
        if (t < 6) stB(1, t + 3);
        BAR(); LGKM0();
        CLUSTER(afB, bfB, 4, 2);
        BAR();
    }

    // ---- epilogue (proven in R4/R5): exp(2*sim), diag mask, row/col sums ----
    asm volatile("s_waitcnt vmcnt(0)" ::: "memory");
    __syncthreads();
    float* rs = (float*)&AL[0][0];     // rowsum[256] | colsum[256]
    float* cs = rs + 256;
    if (tid < 256) { rs[tid] = 0.0f; cs[tid] = 0.0f; }
    __syncthreads();

    float colsum[4] = {0.0f, 0.0f, 0.0f, 0.0f};
    #pragma unroll
    for (int i = 0; i < 8; ++i) {
        #pragma unroll
        for (int r = 0; r < 4; ++r) {
            int lrow = wm + i * 16 + quad * 4 + r;    // local row 0..255
            int grow = rb + lrow;
            float s = 0.0f;
            #pragma unroll
            for (int j = 0; j < 4; ++j) {
                int gcol = cb + wn + j * 16 + m;
                float v  = __expf(2.0f * acc[i][j][r]);
                v = (grow == gcol) ? 0.0f : v;
                s += v;
                colsum[j] += v;
            }
            s += __shfl_xor(s, 1);
            s += __shfl_xor(s, 2);
            s += __shfl_xor(s, 4);
            s += __shfl_xor(s, 8);
            if (m == 0) atomicAdd(&rs[lrow], s);
        }
    }
    if (!diag) {
        #pragma unroll
        for (int j = 0; j < 4; ++j) {
            float s = colsum[j];
            s += __shfl_xor(s, 16);
            s += __shfl_xor(s, 32);
            if (quad == 0) atomicAdd(&cs[wn + j * 16 + m], s);
        }
    }
    __syncthreads();
    if (tid < 256) {
        atomicAdd(&denom[rb + tid], rs[tid]);
        if (!diag) atomicAdd(&denom[cb + tid], cs[tid]);
    }
}

// ---------------------------------------------------------------------------
// Kernel 3: loss (proven, unchanged).
__global__ void loss_kernel(const float* __restrict__ pos,
                            const float* __restrict__ denom,
                            float* __restrict__ out) {
    int r = blockIdx.x * 256 + threadIdx.x;
    float s = __logf(denom[r]) - 2.0f * pos[r & (N_ROWS - 1)];
    for (int o = 32; o; o >>= 1) s += __shfl_down(s, o);
    __shared__ float red[4];
    int t = threadIdx.x;
    if ((t & 63) == 0) red[t >> 6] = s;
    __syncthreads();
    if (t == 0)
        atomicAdd(out, (red[0] + red[1] + red[2] + red[3]) / (float)TWO_N);
}

// ---------------------------------------------------------------------------
extern "C" void kernel_launch(void* const* d_in, const int* in_sizes, int n_in,
                              void* d_out, int out_size, void* d_ws, size_t ws_size,
                              hipStream_t stream) {
    const float* ei = (const float*)d_in[0];
    const float* ej = (const float*)d_in[1];

    unsigned short* zb  = (unsigned short*)d_ws;
    float* pos   = (float*)((char*)d_ws + (size_t)TWO_N * DIM * sizeof(unsigned short));
    float* denom = pos + N_ROWS;
    float* out   = (float*)d_out;

    normalize_kernel<<<N_ROWS, 256, 0, stream>>>(ei, ej, zb, pos, denom, out);
    gemm_exp_kernel<<<NTRI2, 512, 0, stream>>>(zb, denom);
    loss_kernel<<<TWO_N / 256, 256, 0, stream>>>(pos, denom, out);
}